// Round 1
// baseline (106.819 us; speedup 1.0000x reference)
//
#include <hip/hip_runtime.h>

// DensityLoss: out[b,y,x] = loss[b,y,x] * (fg ? 10 : 1) / (H*W) / B
// fg = pixel covered by >= 1 of 64 half-open boxes (x1,y1,x2,y2) per batch.
// B=8, H=W=1024, N=64. pred_densities is unused by the math.
//
// Strategy: one block per row. Build a 1024-bit coverage mask in LDS
// (32 u32 words), 8-way box-split so each thread tests only 8 boxes.
// Each thread then does one float4 load + one float4 store (memory-bound).
//
// Numerics: /2^20 then /8 are exact power-of-2 scalings, so
// (loss*w) * 0x1p-23f is bit-exact vs the reference.

#define NBOX 64
#define WIDTH 1024

__global__ __launch_bounds__(256) void density_loss_row_kernel(
    const float* __restrict__ loss,
    const int*   __restrict__ bboxes,
    float*       __restrict__ out)
{
    __shared__ int4 sbox[NBOX];          // (x1,y1,x2,y2)
    __shared__ unsigned int part[256];   // partial coverage words

    const int t   = threadIdx.x;
    const int row = blockIdx.x;          // b*1024 + y
    const int b   = row >> 10;
    const int y   = row & 1023;

    // stage this batch's boxes into LDS (64 x int4 = 1 KB)
    if (t < NBOX)
        sbox[t] = reinterpret_cast<const int4*>(bboxes)[b * NBOX + t];
    __syncthreads();

    // coverage word (t>>3) vs box group (t&7): 8 box tests per thread
    {
        const int word = t >> 3;             // 0..31
        const int g    = t & 7;              // 0..7
        const int lo_w = word << 5;          // first pixel of this word
        unsigned int m = 0u;
        #pragma unroll
        for (int j = 0; j < 8; ++j) {
            const int4 bx = sbox[g * 8 + j]; // x1,y1,x2,y2
            const bool yin = (y >= bx.y) && (y < bx.w);
            const int lo = max(bx.x, lo_w);
            const int hi = min(bx.z, lo_w + 32);
            if (yin && (lo < hi)) {
                const int len = hi - lo;
                const unsigned int mask =
                    (len >= 32) ? 0xFFFFFFFFu : ((1u << len) - 1u);
                m |= mask << (lo - lo_w);
            }
        }
        part[t] = m;
    }
    __syncthreads();

    // fold the 8 partials for my word (same-address broadcast / 2-way, free)
    const int wbase = (t >> 3) << 3;     // (t & ~7)
    const unsigned int cov =
        part[wbase + 0] | part[wbase + 1] | part[wbase + 2] | part[wbase + 3] |
        part[wbase + 4] | part[wbase + 5] | part[wbase + 6] | part[wbase + 7];

    // 4 pixels per thread: one float4 in, one float4 out
    const size_t base = (size_t)row * WIDTH;
    const float4 l = reinterpret_cast<const float4*>(loss + base)[t];
    const int sh = (t & 7) << 2;         // bit offset of pixel 4t within word
    const float C = 0x1p-23f;            // 1/(H*W)/B, exact

    float4 o;
    o.x = (l.x * (((cov >> (sh + 0)) & 1u) ? 10.0f : 1.0f)) * C;
    o.y = (l.y * (((cov >> (sh + 1)) & 1u) ? 10.0f : 1.0f)) * C;
    o.z = (l.z * (((cov >> (sh + 2)) & 1u) ? 10.0f : 1.0f)) * C;
    o.w = (l.w * (((cov >> (sh + 3)) & 1u) ? 10.0f : 1.0f)) * C;
    reinterpret_cast<float4*>(out + base)[t] = o;
}

extern "C" void kernel_launch(void* const* d_in, const int* in_sizes, int n_in,
                              void* d_out, int out_size, void* d_ws, size_t ws_size,
                              hipStream_t stream) {
    const float* loss   = (const float*)d_in[0];
    // d_in[1] = pred_densities: unused by the reference math
    const int*   bboxes = (const int*)d_in[2];
    float*       out    = (float*)d_out;

    const int n_rows = 8 * 1024;  // B * H
    density_loss_row_kernel<<<dim3(n_rows), dim3(256), 0, stream>>>(loss, bboxes, out);
}